// Round 12
// baseline (20.388 us; speedup 1.0000x reference)
//
#include <hip/hip_runtime.h>

#define BB 64
#define NN 512
#define DD 3
#define EPSF 1e-7f
#define SPLIT 32               // edge blocks per sample; 2048 blocks total
#define NBLK (BB * SPLIT)

// ws (floats):
//   [0 .. NBLK)        edge BCE partial per (s, x)  -- written unconditionally by every edge block
//   [NBLK .. +BB)      n per sample                 -- written by prep
//   [NBLK+BB .. +2BB)  coord SE per sample          -- written by prep
#define WS_EDGE 0
#define WS_N    NBLK
#define WS_SE   (NBLK + BB)

__global__ __launch_bounds__(256) void prep_kernel(const float* __restrict__ pc,
                                                   const float* __restrict__ pts,
                                                   const int* __restrict__ masks,
                                                   float* __restrict__ ws) {
    const int s    = blockIdx.x;
    const int tid  = threadIdx.x;
    const int wid  = tid >> 6;
    const int lane = tid & 63;

    __shared__ int   s_cnt4[4];
    __shared__ float s_cpart[4];

    // n = popcount of prefix mask via 2 ballots per wave
    const int2 mv = ((const int2*)(masks + s * NN))[tid];
    const unsigned long long bl0 = __ballot(mv.x != 0);
    const unsigned long long bl1 = __ballot(mv.y != 0);
    if (lane == 0) s_cnt4[wid] = __popcll(bl0) + __popcll(bl1);
    __syncthreads();
    const int n = s_cnt4[0] + s_cnt4[1] + s_cnt4[2] + s_cnt4[3];

    // coord SE over the first n nodes
    const float* pcb = pc  + s * (NN * DD);
    const float* ptb = pts + s * (NN * DD);
    float se = 0.f;
    for (int e = tid; e < NN * DD; e += 256) {
        if (e < n * DD) {                // prefix mask: element valid iff e < n*DD
            const float d = pcb[e] - ptb[e];
            se += d * d;
        }
    }
#pragma unroll
    for (int off = 32; off; off >>= 1) se += __shfl_xor(se, off);
    if (lane == 0) s_cpart[wid] = se;
    __syncthreads();

    if (tid == 0) {
        ws[WS_N + s]  = (float)n;
        ws[WS_SE + s] = s_cpart[0] + s_cpart[1] + s_cpart[2] + s_cpart[3];
    }
}

__device__ __forceinline__ float row_bce(const float4 p0, const float4 p1,
                                         const float4 q0, const float4 q1,
                                         int e /* = n - j0, >= 1 */) {
    const float pv[8] = {p0.x, p0.y, p0.z, p0.w, p1.x, p1.y, p1.z, p1.w};
    const float av[8] = {q0.x, q0.y, q0.z, q0.w, q1.x, q1.y, q1.z, q1.w};
    float prod0 = 1.f, prod1 = 1.f;
    if (e >= 8) {                       // common fast path: all 8 cols valid
#pragma unroll
        for (int k = 0; k < 4; ++k) {
            // a ∈ {0,1}: bce = -log(clamp(a ? p : 1-p)); 1-clamp(p) == clamp(1-p)
            float r = (av[k] != 0.f) ? pv[k] : 1.f - pv[k];
            prod0 *= fminf(fmaxf(r, EPSF), 1.f - EPSF);
            r = (av[k + 4] != 0.f) ? pv[k + 4] : 1.f - pv[k + 4];
            prod1 *= fminf(fmaxf(r, EPSF), 1.f - EPSF);
        }
    } else {                            // boundary lane (<=1 per row)
#pragma unroll
        for (int k = 0; k < 8; ++k) {
            if (k < e) {
                const float r = (av[k] != 0.f) ? pv[k] : 1.f - pv[k];
                const float q = fminf(fmaxf(r, EPSF), 1.f - EPSF);
                if (k < 4) prod0 *= q; else prod1 *= q;
            }
        }
    }
    // min product = (1e-6)^4 = 1e-24 > FLT_MIN: no underflow
    return -(__logf(prod0) + __logf(prod1));
}

__global__ __launch_bounds__(256) void edge_kernel(const float* __restrict__ am,
                                                   const float* __restrict__ adj,
                                                   const float* __restrict__ ws_n,
                                                   float* __restrict__ ws) {
    const int bid  = blockIdx.x;
    const int s    = bid >> 5;          // sample
    const int x    = bid & 31;          // row-offset within sample
    const int tid  = threadIdx.x;
    const int wid  = tid >> 6;
    const int lane = tid & 63;
    const int j0   = lane * 8;          // this lane's 8-float column slice

    __shared__ float s_part[4];

    // n: single wave-uniform scalar load (L2-hot) — no ballot, no barrier before loads
    const int n = (int)ws_n[s];

    // wave wid owns rows r_t = x + 32*(wid + 4t), t=0..3; issue ALL loads up-front
    const size_t bbase = (size_t)s * NN * NN;
    const bool cols = (j0 < n);
    bool v[4];
    float4 P0[4], P1[4], Q0[4], Q1[4];
#pragma unroll
    for (int t = 0; t < 4; ++t) {
        const int r = x + 32 * (wid + 4 * t);
        v[t] = cols && (r < n);
        if (v[t]) {
            const float* rp = am  + bbase + (size_t)r * NN + j0;
            const float* rq = adj + bbase + (size_t)r * NN + j0;
            P0[t] = *(const float4*)rp;       P1[t] = *(const float4*)(rp + 4);
            Q0[t] = *(const float4*)rq;       Q1[t] = *(const float4*)(rq + 4);
        }
    }

    float sum = 0.f;
    const int e = n - j0;
#pragma unroll
    for (int t = 0; t < 4; ++t) {
        if (v[t]) sum += row_bce(P0[t], P1[t], Q0[t], Q1[t], e);
    }
#pragma unroll
    for (int off = 32; off; off >>= 1) sum += __shfl_xor(sum, off);
    if (lane == 0) s_part[wid] = sum;
    __syncthreads();

    if (tid == 0)
        ws[WS_EDGE + s * SPLIT + x] = s_part[0] + s_part[1] + s_part[2] + s_part[3];
}

__global__ __launch_bounds__(64) void final_kernel(const float* __restrict__ ws,
                                                   const float* __restrict__ counts,
                                                   float* __restrict__ out) {
    const int b = threadIdx.x;   // 64 threads == B samples

    const float4* ep = (const float4*)(ws + WS_EDGE + b * SPLIT);
    float es = 0.f;
#pragma unroll
    for (int k = 0; k < SPLIT / 4; ++k) {
        const float4 v = ep[k];
        es += v.x + v.y + v.z + v.w;
    }

    const float n  = ws[WS_N + b];
    const float se = ws[WS_SE + b];

    const float coord_b = se / fmaxf(n * (float)DD, 1.f);
    const float edge_b  = es / fmaxf(n * n, 1.f);
    const float valid   = (n > 0.f) ? 1.f : 0.f;
    const float dc      = counts[b] - n;

    float v0 = valid;
    float v1 = coord_b * valid;
    float v2 = edge_b * valid;
    float v3 = dc * dc;
#pragma unroll
    for (int off = 32; off > 0; off >>= 1) {
        v0 += __shfl_down(v0, off);
        v1 += __shfl_down(v1, off);
        v2 += __shfl_down(v2, off);
        v3 += __shfl_down(v3, off);
    }
    if (b == 0) {
        const float vc = v0;
        const float denom = fmaxf(vc, 1.f);
        const float coord_loss = (vc > 0.f) ? (v1 / denom) : 0.f;
        const float edge_loss  = (vc > 0.f) ? (v2 / denom) : 0.f;
        const float count_loss = v3 / (float)BB;
        out[0] = coord_loss + edge_loss + 0.1f * count_loss;  // total
        out[1] = coord_loss;
        out[2] = edge_loss;
        out[3] = count_loss;
    }
}

extern "C" void kernel_launch(void* const* d_in, const int* in_sizes, int n_in,
                              void* d_out, int out_size, void* d_ws, size_t ws_size,
                              hipStream_t stream) {
    const float* pc    = (const float*)d_in[0];  // predicted_coords [B,N,D]
    const float* am    = (const float*)d_in[1];  // adjacency_matrix [B,N,N]
    const float* nc    = (const float*)d_in[2];  // node_counts [B,1]
    const float* pts   = (const float*)d_in[3];  // points [B,N,D]
    const float* adj   = (const float*)d_in[4];  // adjacency [B,N,N]
    const int*   masks = (const int*)d_in[5];    // node_masks [B,N]
    float* ws  = (float*)d_ws;
    float* out = (float*)d_out;

    prep_kernel<<<BB, 256, 0, stream>>>(pc, pts, masks, ws);
    edge_kernel<<<NBLK, 256, 0, stream>>>(am, adj, ws + WS_N, ws);
    final_kernel<<<1, 64, 0, stream>>>(ws, nc, out);
}

// Round 13
// 18.623 us; speedup vs baseline: 1.0948x; 1.0948x over previous
//
#include <hip/hip_runtime.h>

#define BB 64
#define NN 512
#define DD 3
#define EPSF 1e-7f
#define SPLIT 64               // blocks per sample; 4096 blocks total
#define NBLK (BB * SPLIT)

// ws (floats):
//   [0 .. NBLK)        edge BCE partial per (s, x)  -- written unconditionally by every block
//   [NBLK .. +BB)      n per sample                 -- written by (s, 0)
//   [NBLK+BB .. +2BB)  coord SE per sample          -- written by (s, 0)
#define WS_EDGE 0
#define WS_N    NBLK
#define WS_SE   (NBLK + BB)

__device__ __forceinline__ float row_bce(const float4 p0, const float4 p1,
                                         const float4 q0, const float4 q1,
                                         int e /* = n - j0, >= 1 */) {
    const float pv[8] = {p0.x, p0.y, p0.z, p0.w, p1.x, p1.y, p1.z, p1.w};
    const float av[8] = {q0.x, q0.y, q0.z, q0.w, q1.x, q1.y, q1.z, q1.w};
    float prod0 = 1.f, prod1 = 1.f;
    if (e >= 8) {                       // common fast path: all 8 cols valid
#pragma unroll
        for (int k = 0; k < 4; ++k) {
            // a ∈ {0,1}: bce = -log(clamp(a ? p : 1-p)); 1-clamp(p) == clamp(1-p)
            float r = (av[k] != 0.f) ? pv[k] : 1.f - pv[k];
            prod0 *= fminf(fmaxf(r, EPSF), 1.f - EPSF);
            r = (av[k + 4] != 0.f) ? pv[k + 4] : 1.f - pv[k + 4];
            prod1 *= fminf(fmaxf(r, EPSF), 1.f - EPSF);
        }
    } else {                            // boundary lane (<=1 per row)
#pragma unroll
        for (int k = 0; k < 8; ++k) {
            if (k < e) {
                const float r = (av[k] != 0.f) ? pv[k] : 1.f - pv[k];
                const float q = fminf(fmaxf(r, EPSF), 1.f - EPSF);
                if (k < 4) prod0 *= q; else prod1 *= q;
            }
        }
    }
    // min product = (1e-6)^4 = 1e-24 > FLT_MIN: no underflow
    return -(__logf(prod0) + __logf(prod1));
}

__global__ __launch_bounds__(256) void fused_kernel(const float* __restrict__ am,
                                                    const float* __restrict__ adj,
                                                    const float* __restrict__ pc,
                                                    const float* __restrict__ pts,
                                                    const int* __restrict__ masks,
                                                    float* __restrict__ ws) {
    const int bid  = blockIdx.x;
    const int s    = bid >> 6;          // sample
    const int x    = bid & 63;          // row-offset within sample
    const int tid  = threadIdx.x;
    const int wid  = tid >> 6;
    const int lane = tid & 63;
    const int j0   = lane * 8;          // this lane's 8-float column slice

    __shared__ int   s_cnt4[4];
    __shared__ float s_part[4];
    __shared__ float s_cpart[4];

    // ---- n = popcount of prefix mask via 2 ballots per wave (2 KB once per block) ----
    const int2 mv = ((const int2*)(masks + s * NN))[tid];
    const unsigned long long bl0 = __ballot(mv.x != 0);
    const unsigned long long bl1 = __ballot(mv.y != 0);
    if (lane == 0) s_cnt4[wid] = __popcll(bl0) + __popcll(bl1);
    __syncthreads();
    const int n = s_cnt4[0] + s_cnt4[1] + s_cnt4[2] + s_cnt4[3];

    // ---- issue ALL edge loads up-front (8 float4 in flight per wave) ----
    // wave wid owns rows r0 = x + 64*wid and r1 = x + 64*(wid+4); block covers x+64j, j=0..7
    const size_t bbase = (size_t)s * NN * NN;
    const int  r0 = x + 64 * wid;
    const int  r1 = x + 64 * (wid + 4);
    const bool v0 = (r0 < n) && (j0 < n);
    const bool v1 = (r1 < n) && (j0 < n);
    float4 pA0, pA1, qA0, qA1, pB0, pB1, qB0, qB1;
    if (v0) {
        const float* rp = am  + bbase + (size_t)r0 * NN + j0;
        const float* rq = adj + bbase + (size_t)r0 * NN + j0;
        pA0 = *(const float4*)rp;       pA1 = *(const float4*)(rp + 4);
        qA0 = *(const float4*)rq;       qA1 = *(const float4*)(rq + 4);
    }
    if (v1) {
        const float* rp = am  + bbase + (size_t)r1 * NN + j0;
        const float* rq = adj + bbase + (size_t)r1 * NN + j0;
        pB0 = *(const float4*)rp;       pB1 = *(const float4*)(rp + 4);
        qB0 = *(const float4*)rq;       qB1 = *(const float4*)(rq + 4);
    }

    // ---- coord SE (x==0 blocks) — runs while edge loads are in flight ----
    if (x == 0) {
        const float* pcb = pc  + s * (NN * DD);
        const float* ptb = pts + s * (NN * DD);
        float se = 0.f;
        for (int e = tid; e < NN * DD; e += 256) {
            if (e < n * DD) {               // prefix mask: element valid iff e < n*DD
                const float d = pcb[e] - ptb[e];
                se += d * d;
            }
        }
#pragma unroll
        for (int off = 32; off; off >>= 1) se += __shfl_xor(se, off);
        if (lane == 0) s_cpart[wid] = se;
    }

    // ---- edge BCE compute ----
    float sum = 0.f;
    if (v0) sum += row_bce(pA0, pA1, qA0, qA1, n - j0);
    if (v1) sum += row_bce(pB0, pB1, qB0, qB1, n - j0);
#pragma unroll
    for (int off = 32; off; off >>= 1) sum += __shfl_xor(sum, off);
    if (lane == 0) s_part[wid] = sum;
    __syncthreads();

    if (tid == 0) {
        ws[WS_EDGE + s * SPLIT + x] = s_part[0] + s_part[1] + s_part[2] + s_part[3];
        if (x == 0) {
            ws[WS_N + s]  = (float)n;
            ws[WS_SE + s] = s_cpart[0] + s_cpart[1] + s_cpart[2] + s_cpart[3];
        }
    }
}

__global__ __launch_bounds__(64) void final_kernel(const float* __restrict__ ws,
                                                   const float* __restrict__ counts,
                                                   float* __restrict__ out) {
    const int b = threadIdx.x;   // 64 threads == B samples

    const float4* ep = (const float4*)(ws + WS_EDGE + b * SPLIT);
    float es = 0.f;
#pragma unroll
    for (int k = 0; k < SPLIT / 4; ++k) {
        const float4 v = ep[k];
        es += v.x + v.y + v.z + v.w;
    }

    const float n  = ws[WS_N + b];
    const float se = ws[WS_SE + b];

    const float coord_b = se / fmaxf(n * (float)DD, 1.f);
    const float edge_b  = es / fmaxf(n * n, 1.f);
    const float valid   = (n > 0.f) ? 1.f : 0.f;
    const float dc      = counts[b] - n;

    float v0 = valid;
    float v1 = coord_b * valid;
    float v2 = edge_b * valid;
    float v3 = dc * dc;
#pragma unroll
    for (int off = 32; off > 0; off >>= 1) {
        v0 += __shfl_down(v0, off);
        v1 += __shfl_down(v1, off);
        v2 += __shfl_down(v2, off);
        v3 += __shfl_down(v3, off);
    }
    if (b == 0) {
        const float vc = v0;
        const float denom = fmaxf(vc, 1.f);
        const float coord_loss = (vc > 0.f) ? (v1 / denom) : 0.f;
        const float edge_loss  = (vc > 0.f) ? (v2 / denom) : 0.f;
        const float count_loss = v3 / (float)BB;
        out[0] = coord_loss + edge_loss + 0.1f * count_loss;  // total
        out[1] = coord_loss;
        out[2] = edge_loss;
        out[3] = count_loss;
    }
}

extern "C" void kernel_launch(void* const* d_in, const int* in_sizes, int n_in,
                              void* d_out, int out_size, void* d_ws, size_t ws_size,
                              hipStream_t stream) {
    const float* pc    = (const float*)d_in[0];  // predicted_coords [B,N,D]
    const float* am    = (const float*)d_in[1];  // adjacency_matrix [B,N,N]
    const float* nc    = (const float*)d_in[2];  // node_counts [B,1]
    const float* pts   = (const float*)d_in[3];  // points [B,N,D]
    const float* adj   = (const float*)d_in[4];  // adjacency [B,N,N]
    const int*   masks = (const int*)d_in[5];    // node_masks [B,N]
    float* ws  = (float*)d_ws;
    float* out = (float*)d_out;

    fused_kernel<<<NBLK, 256, 0, stream>>>(am, adj, pc, pts, masks, ws);
    final_kernel<<<1, 64, 0, stream>>>(ws, nc, out);
}